// Round 1
// baseline (324.043 us; speedup 1.0000x reference)
//
#include <hip/hip_runtime.h>
#include <stdint.h>

// ---------------------------------------------------------------------------
// SegmentationLoss: binary morphology (17x17 ellipse gradient) + weighted MSE.
//
// edges = dilate(m) & ~erode(m) on the border-flipped binary mask m.
// Ellipse half-widths per |dy| (dy in [-8..8]):  [8,8,8,7,7,6,5,4,0]
// Horizontal dilation radius r == r iterations of radius-1 OR-shift dilation.
// Erosion via complement: erode(m) = ~dilate(~m)  (padding conventions match:
// reference pads +inf for erosion => OOB ignored; complement-dilate pads 0).
//
// ws layout:
//   dbits  : uint64 [24][512][8]          (786,432 B)   packed in_detections
//   planes : uint64 [24][12][8][512]      (9,437,184 B) p=0:m 1..5:dm4..8
//                                                        p=6:~m 7..11:dc4..8
//   sums   : float  [24][2]               Sall, Sedge
//   cnts   : int    [24]                  edge counts
// ---------------------------------------------------------------------------

__device__ __forceinline__ void dil1_step(uint64_t a[8]) {
  uint64_t n[8];
#pragma unroll
  for (int w = 0; w < 8; ++w) {
    uint64_t x = a[w];
    uint64_t lo = (w > 0) ? a[w - 1] : 0ull;
    uint64_t hi = (w < 7) ? a[w + 1] : 0ull;
    n[w] = x | (x << 1) | (x >> 1) | (lo >> 63) | (hi << 63);
  }
#pragma unroll
  for (int w = 0; w < 8; ++w) a[w] = n[w];
}

// Stage 1: ballot-pack in_detections bits. One wave per (g,row,word).
__global__ __launch_bounds__(256) void k_pack(const float* __restrict__ det,
                                              uint64_t* __restrict__ dbits) {
  int wid = __builtin_amdgcn_readfirstlane(blockIdx.x * 4 + (threadIdx.x >> 6));
  int lane = threadIdx.x & 63;
  int g = wid >> 12;            // image index b*3+c
  int rem = wid & 4095;
  int row = rem >> 3;
  int w = rem & 7;
  int b = g / 3, ch = g - 3 * b;
  int j = (w << 6) + lane;
  size_t idx = ((((size_t)b << 9) + row) << 9) + j;
  float d = det[idx * 3 + ch];
  unsigned long long bal = __ballot(d == 1.0f);
  if (lane == 0) dbits[(size_t)wid] = bal;
}

// Stage 2: per row, border-flip + horizontal dilation bit-planes.
__global__ __launch_bounds__(256) void k_planes(const uint64_t* __restrict__ dbits,
                                                uint64_t* __restrict__ planes) {
  int t = blockIdx.x * 256 + threadIdx.x;
  if (t >= 24 * 512) return;
  int g = t >> 9, row = t & 511;
  const uint64_t* src = dbits + ((size_t)t << 3);
  uint64_t m[8];
#pragma unroll
  for (int w = 0; w < 8; ++w) m[w] = src[w];
  // border flips: rows 0/511 flip all; cols 0/511 flip; corners net-unflipped.
  if (row == 0 || row == 511) {
#pragma unroll
    for (int w = 0; w < 8; ++w) m[w] = ~m[w];
  }
  m[0] ^= 1ull;
  m[7] ^= (1ull << 63);

  uint64_t* P = planes + (size_t)g * 12 * 8 * 512 + row;  // + (p*8+w)*512
#pragma unroll
  for (int w = 0; w < 8; ++w) P[(size_t)(0 * 8 + w) * 512] = m[w];

  uint64_t a[8];
#pragma unroll
  for (int w = 0; w < 8; ++w) a[w] = m[w];
#pragma unroll
  for (int r = 1; r <= 8; ++r) {
    dil1_step(a);
    if (r >= 4) {
      int p = r - 3;  // 1..5
#pragma unroll
      for (int w = 0; w < 8; ++w) P[(size_t)(p * 8 + w) * 512] = a[w];
    }
  }
#pragma unroll
  for (int w = 0; w < 8; ++w) a[w] = ~m[w];
#pragma unroll
  for (int w = 0; w < 8; ++w) P[(size_t)(6 * 8 + w) * 512] = a[w];
#pragma unroll
  for (int r = 1; r <= 8; ++r) {
    dil1_step(a);
    if (r >= 4) {
      int p = r + 3;  // 7..11
#pragma unroll
      for (int w = 0; w < 8; ++w) P[(size_t)(p * 8 + w) * 512] = a[w];
    }
  }
}

// Stage 3: vertical combine (wave-uniform scalar loads) + pixel loss sums.
// One wave per (g,row).
__global__ __launch_bounds__(256) void k_main(const uint64_t* __restrict__ dbits,
                                              const uint64_t* __restrict__ planes,
                                              const float* __restrict__ pdet,
                                              float* __restrict__ sums,
                                              int* __restrict__ cnts) {
  int wid = __builtin_amdgcn_readfirstlane(blockIdx.x * 4 + (threadIdx.x >> 6));
  int lane = threadIdx.x & 63;
  int g = wid >> 9, row = wid & 511;
  int b = g / 3, ch = g - 3 * b;
  const uint64_t* P = planes + (size_t)g * 12 * 8 * 512;
  const uint64_t* drow = dbits + ((size_t)wid << 3);
  const int PD[9] = {5, 5, 5, 4, 4, 3, 2, 1, 0};  // |dy| -> dil plane

  float s_all = 0.f, s_edge = 0.f;
  int cnt = 0;
#pragma unroll
  for (int w = 0; w < 8; ++w) {
    uint64_t dil = 0ull, erc = 0ull;
#pragma unroll
    for (int dy = -8; dy <= 8; ++dy) {
      int ady = dy < 0 ? -dy : dy;
      int r2 = row + dy;
      int r2c = r2 < 0 ? 0 : (r2 > 511 ? 511 : r2);
      uint64_t ok = (r2 == r2c) ? ~0ull : 0ull;  // uniform mask (OOB rows ignored)
      dil |= P[(size_t)(PD[ady] * 8 + w) * 512 + r2c] & ok;
      erc |= P[(size_t)((PD[ady] + 6) * 8 + w) * 512 + r2c] & ok;
    }
    uint64_t edge = dil & erc;  // dilate & ~erode  (erode = ~erc-combine)
    cnt += (int)__popcll(edge);
    uint64_t dword = drow[w];
    int j = (w << 6) + lane;
    size_t idx = ((((size_t)b << 9) + row) << 9) + j;
    float p = pdet[idx * 3 + ch];
    bool d1 = (dword >> lane) & 1ull;
    float v = d1 ? (1.0f - p) : p;
    v = fmaxf(v, 0.0f);
    float pix = v * v;
    s_all += pix;
    if ((edge >> lane) & 1ull) s_edge += pix;
  }
#pragma unroll
  for (int off = 32; off >= 1; off >>= 1) {
    s_all += __shfl_xor(s_all, off);
    s_edge += __shfl_xor(s_edge, off);
  }
  if (lane == 0) {
    atomicAdd(&sums[2 * g + 0], s_all);
    atomicAdd(&sums[2 * g + 1], s_edge);
    atomicAdd(&cnts[g], cnt);
  }
}

// Stage 4: final 24 -> 8 combine.
__global__ __launch_bounds__(64) void k_final(const float* __restrict__ sums,
                                              const int* __restrict__ cnts,
                                              const float* __restrict__ in_masks,
                                              const float* __restrict__ ew,
                                              const float* __restrict__ lv,
                                              float* __restrict__ out) {
  int b = threadIdx.x;
  if (b >= 8) return;
  float acc = 0.f;
#pragma unroll
  for (int ch = 0; ch < 3; ++ch) {
    int g = b * 3 + ch;
    float w1 = ew[ch] - 1.0f;
    float S = 262144.0f + w1 * (float)cnts[g];
    float raw = (sums[2 * g + 0] + w1 * sums[2 * g + 1]) / S;
    float loss = expf(-lv[ch]) * raw + lv[ch];
    acc += in_masks[g] * loss;
  }
  out[b] = acc * (1.0f / 3.0f);
}

extern "C" void kernel_launch(void* const* d_in, const int* in_sizes, int n_in,
                              void* d_out, int out_size, void* d_ws, size_t ws_size,
                              hipStream_t stream) {
  const float* in_masks = (const float*)d_in[0];
  const float* det = (const float*)d_in[1];
  const float* pdet = (const float*)d_in[2];
  const float* ew = (const float*)d_in[3];
  const float* lv = (const float*)d_in[4];
  float* out = (float*)d_out;

  uint64_t* dbits = (uint64_t*)d_ws;                      // 24*512*8 words
  uint64_t* planes = dbits + (size_t)24 * 512 * 8;        // 24*12*8*512 words
  float* sums = (float*)(planes + (size_t)24 * 12 * 8 * 512);
  int* cnts = (int*)(sums + 48);

  hipMemsetAsync(sums, 0, 48 * sizeof(float) + 24 * sizeof(int), stream);
  k_pack<<<24576, 256, 0, stream>>>(det, dbits);
  k_planes<<<48, 256, 0, stream>>>(dbits, planes);
  k_main<<<3072, 256, 0, stream>>>(dbits, planes, pdet, sums, cnts);
  k_final<<<1, 64, 0, stream>>>(sums, cnts, in_masks, ew, lv, out);
}

// Round 2
// 51.103 us; speedup vs baseline: 6.3410x; 6.3410x over previous
//
#include <hip/hip_runtime.h>
#include <stdint.h>

// ---------------------------------------------------------------------------
// SegmentationLoss: binary morphology (17x17 ellipse gradient) + weighted MSE.
//
// edges = dilate(m) & erc  where erc = dilate(~m)  (erode = ~erc).
// Ellipse half-widths per |dy|: [8,8,8,7,7,6,5,4,0].
//
// Pipeline (all bit-packed, 64 px/word, 8 words/row):
//   k_pack   : ballot-pack det bits, 3 channels per wave (coalesced float3)
//   k_planes : per row: border-flip + horizontal dilation bit-planes r=4..8
//   k_edges  : thread per (g,w,row): lane-parallel vertical OR-combine
//              (coalesced dwordx2 loads from row-contiguous planes)
//   k_pix    : wave per (b,row): pdet read once, 3 channels, edge/det words
//              as wave-uniform scalar loads; partial sums -> slotted atomics
//   k_final  : tiny combine -> out[8]
//
// ws layout:
//   dbits  : uint64 [24][512][8]        786,432 B
//   planes : uint64 [24][12][8][512]  9,437,184 B   p=0:m 1..5:dm4..8
//   edges  : uint64 [24][8][512]        786,432 B   p=6:~m 7..11:dc4..8
//   sums   : float  [48][16]              3,072 B   (g,k) x slot
//   cnts   : int    [24][16]              1,536 B
// ---------------------------------------------------------------------------

#define NSLOT 16

__device__ __forceinline__ void dil1_step(uint64_t a[8]) {
  uint64_t n[8];
#pragma unroll
  for (int w = 0; w < 8; ++w) {
    uint64_t x = a[w];
    uint64_t lo = (w > 0) ? a[w - 1] : 0ull;
    uint64_t hi = (w < 7) ? a[w + 1] : 0ull;
    n[w] = x | (x << 1) | (x >> 1) | (lo >> 63) | (hi << 63);
  }
#pragma unroll
  for (int w = 0; w < 8; ++w) a[w] = n[w];
}

// Stage 1: pack det bits. One wave per (b,row,word), 3 channels at once.
__global__ __launch_bounds__(256) void k_pack(const float* __restrict__ det,
                                              uint64_t* __restrict__ dbits) {
  int wid = __builtin_amdgcn_readfirstlane(blockIdx.x * 4 + (threadIdx.x >> 6));
  int lane = threadIdx.x & 63;
  int b = wid >> 12;
  int rem = wid & 4095;
  int row = rem >> 3;
  int w = rem & 7;
  int j = (w << 6) + lane;
  size_t base = (((((size_t)b << 9) + row) << 9) + j) * 3;
  float d0 = det[base + 0], d1 = det[base + 1], d2 = det[base + 2];
  unsigned long long b0 = __ballot(d0 == 1.0f);
  unsigned long long b1 = __ballot(d1 == 1.0f);
  unsigned long long b2 = __ballot(d2 == 1.0f);
  if (lane == 0) {
    size_t o = ((size_t)row << 3) + w;
    dbits[(((size_t)(b * 3 + 0)) << 12) + o] = b0;
    dbits[(((size_t)(b * 3 + 1)) << 12) + o] = b1;
    dbits[(((size_t)(b * 3 + 2)) << 12) + o] = b2;
  }
}

// Stage 2: per row, border-flip + horizontal dilation bit-planes.
__global__ __launch_bounds__(256) void k_planes(const uint64_t* __restrict__ dbits,
                                                uint64_t* __restrict__ planes) {
  int t = blockIdx.x * 256 + threadIdx.x;
  if (t >= 24 * 512) return;
  int g = t >> 9, row = t & 511;
  const uint64_t* src = dbits + ((size_t)t << 3);
  uint64_t m[8];
#pragma unroll
  for (int w = 0; w < 8; ++w) m[w] = src[w];
  if (row == 0 || row == 511) {
#pragma unroll
    for (int w = 0; w < 8; ++w) m[w] = ~m[w];
  }
  m[0] ^= 1ull;
  m[7] ^= (1ull << 63);

  uint64_t* P = planes + (size_t)g * 12 * 8 * 512 + row;  // + (p*8+w)*512
#pragma unroll
  for (int w = 0; w < 8; ++w) P[(size_t)(0 * 8 + w) * 512] = m[w];

  uint64_t a[8];
#pragma unroll
  for (int w = 0; w < 8; ++w) a[w] = m[w];
#pragma unroll
  for (int r = 1; r <= 8; ++r) {
    dil1_step(a);
    if (r >= 4) {
      int p = r - 3;
#pragma unroll
      for (int w = 0; w < 8; ++w) P[(size_t)(p * 8 + w) * 512] = a[w];
    }
  }
#pragma unroll
  for (int w = 0; w < 8; ++w) a[w] = ~m[w];
#pragma unroll
  for (int w = 0; w < 8; ++w) P[(size_t)(6 * 8 + w) * 512] = a[w];
#pragma unroll
  for (int r = 1; r <= 8; ++r) {
    dil1_step(a);
    if (r >= 4) {
      int p = r + 3;
#pragma unroll
      for (int w = 0; w < 8; ++w) P[(size_t)(p * 8 + w) * 512] = a[w];
    }
  }
}

// Stage 3: lane-parallel vertical combine. Thread per (g,w,row).
__global__ __launch_bounds__(256) void k_edges(const uint64_t* __restrict__ planes,
                                               uint64_t* __restrict__ edges,
                                               int* __restrict__ cnts) {
  int t = blockIdx.x * 256 + threadIdx.x;   // 24*8*512 threads
  int g = t >> 12;
  int rem = t & 4095;
  int w = rem >> 9;
  int row = rem & 511;
  const uint64_t* P = planes + (size_t)g * 12 * 8 * 512;
  const int PD[9] = {5, 5, 5, 4, 4, 3, 2, 1, 0};

  uint64_t dil = 0ull, erc = 0ull;
#pragma unroll
  for (int dy = -8; dy <= 8; ++dy) {
    int ady = dy < 0 ? -dy : dy;
    int r2 = row + dy;
    int r2c = r2 < 0 ? 0 : (r2 > 511 ? 511 : r2);
    uint64_t ok = (r2 == r2c) ? ~0ull : 0ull;
    dil |= P[(size_t)(PD[ady] * 8 + w) * 512 + r2c] & ok;
    erc |= P[(size_t)((PD[ady] + 6) * 8 + w) * 512 + r2c] & ok;
  }
  uint64_t edge = dil & erc;
  edges[(size_t)t] = edge;   // layout [g][w][row], row-contiguous

  int c = (int)__popcll(edge);
#pragma unroll
  for (int off = 32; off >= 1; off >>= 1) c += __shfl_xor(c, off);
  int lane = threadIdx.x & 63;
  if (lane == 0) {
    int wid = t >> 6;
    atomicAdd(&cnts[g * NSLOT + (wid & (NSLOT - 1))], c);
  }
}

// Stage 4: pixel loss sums. One wave per (b,row), 3 channels.
__global__ __launch_bounds__(256) void k_pix(const uint64_t* __restrict__ dbits,
                                             const uint64_t* __restrict__ edges,
                                             const float* __restrict__ pdet,
                                             float* __restrict__ sums) {
  int wid = __builtin_amdgcn_readfirstlane(blockIdx.x * 4 + (threadIdx.x >> 6));
  int lane = threadIdx.x & 63;
  int b = wid >> 9, row = wid & 511;
  float sA0 = 0.f, sA1 = 0.f, sA2 = 0.f;
  float sE0 = 0.f, sE1 = 0.f, sE2 = 0.f;
#pragma unroll
  for (int w = 0; w < 8; ++w) {
    int j = (w << 6) + lane;
    size_t base = (((((size_t)b << 9) + row) << 9) + j) * 3;
    float p0 = pdet[base + 0], p1 = pdet[base + 1], p2 = pdet[base + 2];
#pragma unroll
    for (int ch = 0; ch < 3; ++ch) {
      int g = b * 3 + ch;
      uint64_t D = dbits[(((size_t)g) << 12) + ((size_t)row << 3) + w];
      uint64_t E = edges[((size_t)(g * 8 + w) << 9) + row];
      float p = ch == 0 ? p0 : (ch == 1 ? p1 : p2);
      bool d1 = (D >> lane) & 1ull;
      float v = d1 ? (1.0f - p) : p;
      v = fmaxf(v, 0.0f);
      float pix = v * v;
      float* sA = ch == 0 ? &sA0 : (ch == 1 ? &sA1 : &sA2);
      float* sE = ch == 0 ? &sE0 : (ch == 1 ? &sE1 : &sE2);
      *sA += pix;
      if ((E >> lane) & 1ull) *sE += pix;
    }
  }
#pragma unroll
  for (int off = 32; off >= 1; off >>= 1) {
    sA0 += __shfl_xor(sA0, off);
    sA1 += __shfl_xor(sA1, off);
    sA2 += __shfl_xor(sA2, off);
    sE0 += __shfl_xor(sE0, off);
    sE1 += __shfl_xor(sE1, off);
    sE2 += __shfl_xor(sE2, off);
  }
  if (lane == 0) {
    int slot = wid & (NSLOT - 1);
    int g = b * 3;
    atomicAdd(&sums[(2 * (g + 0) + 0) * NSLOT + slot], sA0);
    atomicAdd(&sums[(2 * (g + 0) + 1) * NSLOT + slot], sE0);
    atomicAdd(&sums[(2 * (g + 1) + 0) * NSLOT + slot], sA1);
    atomicAdd(&sums[(2 * (g + 1) + 1) * NSLOT + slot], sE1);
    atomicAdd(&sums[(2 * (g + 2) + 0) * NSLOT + slot], sA2);
    atomicAdd(&sums[(2 * (g + 2) + 1) * NSLOT + slot], sE2);
  }
}

// Stage 5: final combine.
__global__ __launch_bounds__(64) void k_final(const float* __restrict__ sums,
                                              const int* __restrict__ cnts,
                                              const float* __restrict__ in_masks,
                                              const float* __restrict__ ew,
                                              const float* __restrict__ lv,
                                              float* __restrict__ out) {
  int b = threadIdx.x;
  if (b >= 8) return;
  float acc = 0.f;
#pragma unroll
  for (int ch = 0; ch < 3; ++ch) {
    int g = b * 3 + ch;
    float sAll = 0.f, sEdge = 0.f;
    float cnt = 0.f;
    for (int s = 0; s < NSLOT; ++s) {
      sAll += sums[(2 * g + 0) * NSLOT + s];
      sEdge += sums[(2 * g + 1) * NSLOT + s];
      cnt += (float)cnts[g * NSLOT + s];
    }
    float w1 = ew[ch] - 1.0f;
    float S = 262144.0f + w1 * cnt;
    float raw = (sAll + w1 * sEdge) / S;
    float loss = expf(-lv[ch]) * raw + lv[ch];
    acc += in_masks[g] * loss;
  }
  out[b] = acc * (1.0f / 3.0f);
}

extern "C" void kernel_launch(void* const* d_in, const int* in_sizes, int n_in,
                              void* d_out, int out_size, void* d_ws, size_t ws_size,
                              hipStream_t stream) {
  const float* in_masks = (const float*)d_in[0];
  const float* det = (const float*)d_in[1];
  const float* pdet = (const float*)d_in[2];
  const float* ew = (const float*)d_in[3];
  const float* lv = (const float*)d_in[4];
  float* out = (float*)d_out;

  uint64_t* dbits = (uint64_t*)d_ws;                       // 24*512*8
  uint64_t* planes = dbits + (size_t)24 * 512 * 8;         // 24*12*8*512
  uint64_t* edges = planes + (size_t)24 * 12 * 8 * 512;    // 24*8*512
  float* sums = (float*)(edges + (size_t)24 * 8 * 512);    // 48*NSLOT
  int* cnts = (int*)(sums + 48 * NSLOT);                   // 24*NSLOT

  hipMemsetAsync(sums, 0, (48 * NSLOT) * sizeof(float) + (24 * NSLOT) * sizeof(int),
                 stream);
  k_pack<<<8192, 256, 0, stream>>>(det, dbits);
  k_planes<<<48, 256, 0, stream>>>(dbits, planes);
  k_edges<<<384, 256, 0, stream>>>(planes, edges, cnts);
  k_pix<<<1024, 256, 0, stream>>>(dbits, edges, pdet, sums);
  k_final<<<1, 64, 0, stream>>>(sums, cnts, in_masks, ew, lv, out);
}

// Round 3
// 45.760 us; speedup vs baseline: 7.0814x; 1.1168x over previous
//
#include <hip/hip_runtime.h>
#include <stdint.h>

// ---------------------------------------------------------------------------
// SegmentationLoss: binary morphology (17x17 ellipse gradient) + weighted MSE.
//
// edges = dilate(m) & erc  where erc = dilate(~m)  (erode = ~erc).
// Ellipse half-widths per |dy|: [8,8,8,7,7,6,5,4,0].
//
// Pipeline (all bit-packed, 64 px/word, 8 words/row):
//   k_pack   : ballot-pack det bits (3 ch/wave); block 0 zeroes accumulators
//   k_planes : per row: border-flip + horizontal dilation bit-planes r=4..8
//   k_edges  : thread per (g,w,row): lane-parallel vertical OR-combine
//   k_pix    : wave per (b,row): pdet read once, 3 channels
//   k_final  : tiny combine -> out[8]
//
// ws layout:
//   dbits  : uint64 [24][512][8]        786,432 B
//   planes : uint64 [24][12][8][512]  9,437,184 B   p=0:m 1..5:dm4..8
//   edges  : uint64 [24][8][512]        786,432 B   p=6:~m 7..11:dc4..8
//   sums   : float  [48][16]              3,072 B   (g,k) x slot
//   cnts   : int    [24][16]              1,536 B   (contiguous after sums)
// ---------------------------------------------------------------------------

#define NSLOT 16

__device__ __forceinline__ void dil1_step(uint64_t a[8]) {
  uint64_t n[8];
#pragma unroll
  for (int w = 0; w < 8; ++w) {
    uint64_t x = a[w];
    uint64_t lo = (w > 0) ? a[w - 1] : 0ull;
    uint64_t hi = (w < 7) ? a[w + 1] : 0ull;
    n[w] = x | (x << 1) | (x >> 1) | (lo >> 63) | (hi << 63);
  }
#pragma unroll
  for (int w = 0; w < 8; ++w) a[w] = n[w];
}

// Stage 1: pack det bits. One wave per (b,row,word), 3 channels at once.
// Block 0 additionally zeroes the sums/cnts accumulator region (read only by
// later kernels -- kernel boundary orders it before any atomicAdd).
__global__ __launch_bounds__(256) void k_pack(const float* __restrict__ det,
                                              uint64_t* __restrict__ dbits,
                                              uint32_t* __restrict__ acc_zero) {
  if (blockIdx.x == 0) {
    // 48*NSLOT floats + 24*NSLOT ints = 1152 dwords
    for (int i = threadIdx.x; i < 72 * NSLOT; i += 256) acc_zero[i] = 0u;
  }
  int wid = __builtin_amdgcn_readfirstlane(blockIdx.x * 4 + (threadIdx.x >> 6));
  int lane = threadIdx.x & 63;
  int b = wid >> 12;
  int rem = wid & 4095;
  int row = rem >> 3;
  int w = rem & 7;
  int j = (w << 6) + lane;
  size_t base = (((((size_t)b << 9) + row) << 9) + j) * 3;
  float d0 = det[base + 0], d1 = det[base + 1], d2 = det[base + 2];
  unsigned long long b0 = __ballot(d0 == 1.0f);
  unsigned long long b1 = __ballot(d1 == 1.0f);
  unsigned long long b2 = __ballot(d2 == 1.0f);
  if (lane == 0) {
    size_t o = ((size_t)row << 3) + w;
    dbits[(((size_t)(b * 3 + 0)) << 12) + o] = b0;
    dbits[(((size_t)(b * 3 + 1)) << 12) + o] = b1;
    dbits[(((size_t)(b * 3 + 2)) << 12) + o] = b2;
  }
}

// Stage 2: per row, border-flip + horizontal dilation bit-planes.
__global__ __launch_bounds__(256) void k_planes(const uint64_t* __restrict__ dbits,
                                                uint64_t* __restrict__ planes) {
  int t = blockIdx.x * 256 + threadIdx.x;
  if (t >= 24 * 512) return;
  int g = t >> 9, row = t & 511;
  const uint64_t* src = dbits + ((size_t)t << 3);
  uint64_t m[8];
#pragma unroll
  for (int w = 0; w < 8; ++w) m[w] = src[w];
  if (row == 0 || row == 511) {
#pragma unroll
    for (int w = 0; w < 8; ++w) m[w] = ~m[w];
  }
  m[0] ^= 1ull;
  m[7] ^= (1ull << 63);

  uint64_t* P = planes + (size_t)g * 12 * 8 * 512 + row;  // + (p*8+w)*512
#pragma unroll
  for (int w = 0; w < 8; ++w) P[(size_t)(0 * 8 + w) * 512] = m[w];

  uint64_t a[8];
#pragma unroll
  for (int w = 0; w < 8; ++w) a[w] = m[w];
#pragma unroll
  for (int r = 1; r <= 8; ++r) {
    dil1_step(a);
    if (r >= 4) {
      int p = r - 3;
#pragma unroll
      for (int w = 0; w < 8; ++w) P[(size_t)(p * 8 + w) * 512] = a[w];
    }
  }
#pragma unroll
  for (int w = 0; w < 8; ++w) a[w] = ~m[w];
#pragma unroll
  for (int w = 0; w < 8; ++w) P[(size_t)(6 * 8 + w) * 512] = a[w];
#pragma unroll
  for (int r = 1; r <= 8; ++r) {
    dil1_step(a);
    if (r >= 4) {
      int p = r + 3;
#pragma unroll
      for (int w = 0; w < 8; ++w) P[(size_t)(p * 8 + w) * 512] = a[w];
    }
  }
}

// Stage 3: lane-parallel vertical combine. Thread per (g,w,row).
__global__ __launch_bounds__(256) void k_edges(const uint64_t* __restrict__ planes,
                                               uint64_t* __restrict__ edges,
                                               int* __restrict__ cnts) {
  int t = blockIdx.x * 256 + threadIdx.x;   // 24*8*512 threads
  int g = t >> 12;
  int rem = t & 4095;
  int w = rem >> 9;
  int row = rem & 511;
  const uint64_t* P = planes + (size_t)g * 12 * 8 * 512;
  const int PD[9] = {5, 5, 5, 4, 4, 3, 2, 1, 0};

  uint64_t dil = 0ull, erc = 0ull;
#pragma unroll
  for (int dy = -8; dy <= 8; ++dy) {
    int ady = dy < 0 ? -dy : dy;
    int r2 = row + dy;
    int r2c = r2 < 0 ? 0 : (r2 > 511 ? 511 : r2);
    uint64_t ok = (r2 == r2c) ? ~0ull : 0ull;
    dil |= P[(size_t)(PD[ady] * 8 + w) * 512 + r2c] & ok;
    erc |= P[(size_t)((PD[ady] + 6) * 8 + w) * 512 + r2c] & ok;
  }
  uint64_t edge = dil & erc;
  edges[(size_t)t] = edge;   // layout [g][w][row], row-contiguous

  int c = (int)__popcll(edge);
#pragma unroll
  for (int off = 32; off >= 1; off >>= 1) c += __shfl_xor(c, off);
  int lane = threadIdx.x & 63;
  if (lane == 0) {
    int wid = t >> 6;
    atomicAdd(&cnts[g * NSLOT + (wid & (NSLOT - 1))], c);
  }
}

// Stage 4: pixel loss sums. One wave per (b,row), 3 channels.
__global__ __launch_bounds__(256) void k_pix(const uint64_t* __restrict__ dbits,
                                             const uint64_t* __restrict__ edges,
                                             const float* __restrict__ pdet,
                                             float* __restrict__ sums) {
  int wid = __builtin_amdgcn_readfirstlane(blockIdx.x * 4 + (threadIdx.x >> 6));
  int lane = threadIdx.x & 63;
  int b = wid >> 9, row = wid & 511;
  float sA0 = 0.f, sA1 = 0.f, sA2 = 0.f;
  float sE0 = 0.f, sE1 = 0.f, sE2 = 0.f;
#pragma unroll
  for (int w = 0; w < 8; ++w) {
    int j = (w << 6) + lane;
    size_t base = (((((size_t)b << 9) + row) << 9) + j) * 3;
    float p0 = pdet[base + 0], p1 = pdet[base + 1], p2 = pdet[base + 2];
#pragma unroll
    for (int ch = 0; ch < 3; ++ch) {
      int g = b * 3 + ch;
      uint64_t D = dbits[(((size_t)g) << 12) + ((size_t)row << 3) + w];
      uint64_t E = edges[((size_t)(g * 8 + w) << 9) + row];
      float p = ch == 0 ? p0 : (ch == 1 ? p1 : p2);
      bool d1 = (D >> lane) & 1ull;
      float v = d1 ? (1.0f - p) : p;
      v = fmaxf(v, 0.0f);
      float pix = v * v;
      float* sA = ch == 0 ? &sA0 : (ch == 1 ? &sA1 : &sA2);
      float* sE = ch == 0 ? &sE0 : (ch == 1 ? &sE1 : &sE2);
      *sA += pix;
      if ((E >> lane) & 1ull) *sE += pix;
    }
  }
#pragma unroll
  for (int off = 32; off >= 1; off >>= 1) {
    sA0 += __shfl_xor(sA0, off);
    sA1 += __shfl_xor(sA1, off);
    sA2 += __shfl_xor(sA2, off);
    sE0 += __shfl_xor(sE0, off);
    sE1 += __shfl_xor(sE1, off);
    sE2 += __shfl_xor(sE2, off);
  }
  if (lane == 0) {
    int slot = wid & (NSLOT - 1);
    int g = b * 3;
    atomicAdd(&sums[(2 * (g + 0) + 0) * NSLOT + slot], sA0);
    atomicAdd(&sums[(2 * (g + 0) + 1) * NSLOT + slot], sE0);
    atomicAdd(&sums[(2 * (g + 1) + 0) * NSLOT + slot], sA1);
    atomicAdd(&sums[(2 * (g + 1) + 1) * NSLOT + slot], sE1);
    atomicAdd(&sums[(2 * (g + 2) + 0) * NSLOT + slot], sA2);
    atomicAdd(&sums[(2 * (g + 2) + 1) * NSLOT + slot], sE2);
  }
}

// Stage 5: final combine.
__global__ __launch_bounds__(64) void k_final(const float* __restrict__ sums,
                                              const int* __restrict__ cnts,
                                              const float* __restrict__ in_masks,
                                              const float* __restrict__ ew,
                                              const float* __restrict__ lv,
                                              float* __restrict__ out) {
  int b = threadIdx.x;
  if (b >= 8) return;
  float acc = 0.f;
#pragma unroll
  for (int ch = 0; ch < 3; ++ch) {
    int g = b * 3 + ch;
    float sAll = 0.f, sEdge = 0.f;
    float cnt = 0.f;
    for (int s = 0; s < NSLOT; ++s) {
      sAll += sums[(2 * g + 0) * NSLOT + s];
      sEdge += sums[(2 * g + 1) * NSLOT + s];
      cnt += (float)cnts[g * NSLOT + s];
    }
    float w1 = ew[ch] - 1.0f;
    float S = 262144.0f + w1 * cnt;
    float raw = (sAll + w1 * sEdge) / S;
    float loss = expf(-lv[ch]) * raw + lv[ch];
    acc += in_masks[g] * loss;
  }
  out[b] = acc * (1.0f / 3.0f);
}

extern "C" void kernel_launch(void* const* d_in, const int* in_sizes, int n_in,
                              void* d_out, int out_size, void* d_ws, size_t ws_size,
                              hipStream_t stream) {
  const float* in_masks = (const float*)d_in[0];
  const float* det = (const float*)d_in[1];
  const float* pdet = (const float*)d_in[2];
  const float* ew = (const float*)d_in[3];
  const float* lv = (const float*)d_in[4];
  float* out = (float*)d_out;

  uint64_t* dbits = (uint64_t*)d_ws;                       // 24*512*8
  uint64_t* planes = dbits + (size_t)24 * 512 * 8;         // 24*12*8*512
  uint64_t* edges = planes + (size_t)24 * 12 * 8 * 512;    // 24*8*512
  float* sums = (float*)(edges + (size_t)24 * 8 * 512);    // 48*NSLOT
  int* cnts = (int*)(sums + 48 * NSLOT);                   // 24*NSLOT

  k_pack<<<8192, 256, 0, stream>>>(det, dbits, (uint32_t*)sums);
  k_planes<<<48, 256, 0, stream>>>(dbits, planes);
  k_edges<<<384, 256, 0, stream>>>(planes, edges, cnts);
  k_pix<<<1024, 256, 0, stream>>>(dbits, edges, pdet, sums);
  k_final<<<1, 64, 0, stream>>>(sums, cnts, in_masks, ew, lv, out);
}

// Round 4
// 24.640 us; speedup vs baseline: 13.1511x; 1.8571x over previous
//
#include <hip/hip_runtime.h>
#include <stdint.h>

// ---------------------------------------------------------------------------
// SegmentationLoss, fully fused: binary 17x17-ellipse morphological gradient
// + weighted MSE, one pass over det/pdet, partials -> tiny final kernel.
//
// edges = dilate(m) & dilate(~m)   (erode = ~dilate(~m); bits, pad-0 == the
// reference's +-inf SAME padding, which ignores OOB on both sides).
// Ellipse half-widths per |dy|: [8,8,8,7,7,6,5,4,0].
//
// Block = (image b, 16-row tile). All morphology in LDS:
//   step 1: ballot-pack det rows [r0-8, r0+23], 3 channels  -> mb
//   per ch: step 2: horizontal dilation planes (shift-OR, radius<=8 => only
//                   adjacent words needed)                   -> pl
//           step 3: vertical OR-combine + popcount           -> eg, cw
//   step 4: pixel loss sums over the 16 owned rows (pdet read once)
//   step 5: per-block partials to distinct global slots (no atomics,
//           no zero-init, bitwise-deterministic)
// ---------------------------------------------------------------------------

#define TILE 16
#define ROWS 32        // TILE + 2*8 halo
#define NT   32        // tiles per image
#define PLS  90        // u64 per plane-row (11 planes * 8 words + pad)

__global__ __launch_bounds__(1024) void k_fused(const float* __restrict__ det,
                                                const float* __restrict__ pdet,
                                                float* __restrict__ partials) {
  __shared__ uint64_t mb[3][ROWS][9];   // original packed bits (padded)
  __shared__ uint64_t pl[ROWS][PLS];    // planes of current ch:
                                        //   0:m(flipped) 1..5:dm4..8 6..10:dc4..8
  __shared__ uint64_t eg[3][TILE][8];   // edge words
  __shared__ float red[16][6];          // per-wave partials sA0..2,sE0..2
  __shared__ int cw[3][2];              // per-ch edge counts (2 waves)

  int blk = blockIdx.x;
  int b = blk & 7;            // same-b blocks -> same XCD (round-robin assumption)
  int tile = blk >> 3;
  int r0 = tile * TILE;
  int tid = threadIdx.x;
  int wv = tid >> 6, lane = tid & 63;

  // ---- step 1: ballot-pack det rows, 3 channels ----
  for (int it = 0; it < 16; ++it) {
    int task = wv * 16 + it;            // (rl, w), 256 tasks
    int rl = task >> 3, w = task & 7;
    int grow = r0 - 8 + rl;
    uint64_t b0 = 0, b1 = 0, b2 = 0;
    if (grow >= 0 && grow < 512) {
      size_t base = (((((size_t)b << 9) + grow) << 9) + (w << 6) + lane) * 3;
      float d0 = det[base], d1 = det[base + 1], d2 = det[base + 2];
      b0 = __ballot(d0 == 1.0f);
      b1 = __ballot(d1 == 1.0f);
      b2 = __ballot(d2 == 1.0f);
    }
    if (lane == 0) { mb[0][rl][w] = b0; mb[1][rl][w] = b1; mb[2][rl][w] = b2; }
  }
  __syncthreads();

  const int PD[9] = {5, 5, 5, 4, 4, 3, 2, 1, 0};  // |dy| -> dil plane (radius)

  for (int ch = 0; ch < 3; ++ch) {
    // ---- step 2: horizontal dilation planes ----
    if (tid < 256) {
      int rl = tid >> 3, w = tid & 7;
      int grow = r0 - 8 + rl;
      bool valid = (grow >= 0 && grow < 512);
      uint64_t x = 0, xl = 0, xh = 0;
      if (valid) {
        x = mb[ch][rl][w];
        xl = (w > 0) ? mb[ch][rl][w - 1] : 0;
        xh = (w < 7) ? mb[ch][rl][w + 1] : 0;
        if (grow == 0 || grow == 511) {          // border row flip
          x = ~x;
          xl = (w > 0) ? ~xl : 0;
          xh = (w < 7) ? ~xh : 0;
        }
        if (w == 0) x ^= 1ull;                   // border col flips
        if (w == 7) x ^= (1ull << 63);
      }
      uint64_t* P = pl[rl];
      P[0 * 8 + w] = x;                          // m (0 for OOB rows)
      uint64_t d = x;
#pragma unroll
      for (int s = 1; s <= 8; ++s) {
        d |= (x << s) | (xl >> (64 - s)) | (x >> s) | (xh << (64 - s));
        if (s >= 4) P[(s - 3) * 8 + w] = d;      // dm4..8 -> 1..5
      }
      uint64_t xc = 0, xlc = 0, xhc = 0;
      if (valid) {
        xc = ~x;
        xlc = (w > 0) ? ~xl : 0;
        xhc = (w < 7) ? ~xh : 0;
      }
      d = xc;
#pragma unroll
      for (int s = 1; s <= 8; ++s) {
        d |= (xc << s) | (xlc >> (64 - s)) | (xc >> s) | (xhc << (64 - s));
        if (s >= 4) P[(s + 2) * 8 + w] = d;      // dc4..8 -> 6..10
      }
    }
    __syncthreads();

    // ---- step 3: vertical combine + popcount ----
    if (tid < 128) {
      int rl = tid >> 3, w = tid & 7;
      uint64_t dil = 0, erc = 0;
#pragma unroll
      for (int dy = -8; dy <= 8; ++dy) {
        int ady = dy < 0 ? -dy : dy;
        int pr = rl + 8 + dy;                    // 0..31
        if (ady == 8) {
          int grow = r0 - 8 + pr;
          uint64_t m = pl[pr][w];
          dil |= m;
          erc |= (grow >= 0 && grow < 512) ? ~m : 0;  // mc derived
        } else {
          dil |= pl[pr][PD[ady] * 8 + w];
          erc |= pl[pr][(PD[ady] + 5) * 8 + w];
        }
      }
      uint64_t e = dil & erc;
      eg[ch][rl][w] = e;
      int c = __popcll(e);
#pragma unroll
      for (int off = 32; off >= 1; off >>= 1) c += __shfl_xor(c, off);
      if (lane == 0) cw[ch][wv] = c;
    }
    __syncthreads();   // also guards pl overwrite by next ch
  }

  // ---- step 4: pixel loss sums over the 16 owned rows ----
  float sA0 = 0, sA1 = 0, sA2 = 0, sE0 = 0, sE1 = 0, sE2 = 0;
#pragma unroll
  for (int it = 0; it < 8; ++it) {
    int task = wv * 8 + it;                      // (rl, w), 128 tasks
    int rl = task >> 3, w = task & 7;
    int grow = r0 + rl;
    size_t base = (((((size_t)b << 9) + grow) << 9) + (w << 6) + lane) * 3;
    float p0 = pdet[base], p1 = pdet[base + 1], p2 = pdet[base + 2];
    uint64_t D0 = mb[0][rl + 8][w], D1 = mb[1][rl + 8][w], D2 = mb[2][rl + 8][w];
    uint64_t E0 = eg[0][rl][w], E1 = eg[1][rl][w], E2 = eg[2][rl][w];
    float v0 = ((D0 >> lane) & 1) ? 1.0f - p0 : p0; v0 = fmaxf(v0, 0.f); v0 *= v0;
    float v1 = ((D1 >> lane) & 1) ? 1.0f - p1 : p1; v1 = fmaxf(v1, 0.f); v1 *= v1;
    float v2 = ((D2 >> lane) & 1) ? 1.0f - p2 : p2; v2 = fmaxf(v2, 0.f); v2 *= v2;
    sA0 += v0; sA1 += v1; sA2 += v2;
    if ((E0 >> lane) & 1) sE0 += v0;
    if ((E1 >> lane) & 1) sE1 += v1;
    if ((E2 >> lane) & 1) sE2 += v2;
  }
#pragma unroll
  for (int off = 32; off >= 1; off >>= 1) {
    sA0 += __shfl_xor(sA0, off); sA1 += __shfl_xor(sA1, off); sA2 += __shfl_xor(sA2, off);
    sE0 += __shfl_xor(sE0, off); sE1 += __shfl_xor(sE1, off); sE2 += __shfl_xor(sE2, off);
  }
  if (lane == 0) {
    red[wv][0] = sA0; red[wv][1] = sA1; red[wv][2] = sA2;
    red[wv][3] = sE0; red[wv][4] = sE1; red[wv][5] = sE2;
  }
  __syncthreads();

  // ---- step 5: per-block partials (distinct slots, no atomics) ----
  if (tid < 6) {
    float s = 0.f;
    for (int i = 0; i < 16; ++i) s += red[i][tid];
    partials[blk * 9 + tid] = s;                 // 0..2 sAll, 3..5 sEdge
  } else if (tid < 9) {
    int ch = tid - 6;
    partials[blk * 9 + tid] = (float)(cw[ch][0] + cw[ch][1]);  // 6..8 cnt
  }
}

// ---- final: 256x9 partials -> out[8] (bitwise-deterministic fixed order) ----
__global__ __launch_bounds__(64) void k_final(const float* __restrict__ partials,
                                              const float* __restrict__ in_masks,
                                              const float* __restrict__ ew,
                                              const float* __restrict__ lv,
                                              float* __restrict__ out) {
  int b = threadIdx.x;
  if (b >= 8) return;
  float acc = 0.f;
  for (int ch = 0; ch < 3; ++ch) {
    float sA = 0.f, sE = 0.f, cn = 0.f;
    for (int t = 0; t < NT; ++t) {
      const float* P = partials + ((t << 3) | b) * 9;
      sA += P[ch]; sE += P[3 + ch]; cn += P[6 + ch];
    }
    float w1 = ew[ch] - 1.0f;
    float S = 262144.0f + w1 * cn;               // H*W + (ew-1)*cnt
    float raw = (sA + w1 * sE) / S;
    float loss = expf(-lv[ch]) * raw + lv[ch];
    acc += in_masks[b * 3 + ch] * loss;
  }
  out[b] = acc * (1.0f / 3.0f);
}

extern "C" void kernel_launch(void* const* d_in, const int* in_sizes, int n_in,
                              void* d_out, int out_size, void* d_ws, size_t ws_size,
                              hipStream_t stream) {
  const float* in_masks = (const float*)d_in[0];
  const float* det = (const float*)d_in[1];
  const float* pdet = (const float*)d_in[2];
  const float* ew = (const float*)d_in[3];
  const float* lv = (const float*)d_in[4];
  float* out = (float*)d_out;

  float* partials = (float*)d_ws;   // [256][9], fully rewritten every call

  k_fused<<<256, 1024, 0, stream>>>(det, pdet, partials);
  k_final<<<1, 64, 0, stream>>>(partials, in_masks, ew, lv, out);
}